// Round 1
// baseline (174.638 us; speedup 1.0000x reference)
//
#include <hip/hip_runtime.h>
#include <hip/hip_bf16.h>

// Problem constants: N=1024, C=32, T=8, V=64, K=3, CT=256
// out[n][c][v][t] = sum_k sum_j W[k][c*8+t][j] * U_k[j][v] + bias2T[c*8+t][v]
// U_k[j][v] = sum_u x[n][j][u] * A[k][u][v]
//
// R6: w-split x2. R5 was latency-bound (MfmaUtil 21%, VALUBusy 14%, HBM 22%,
// Occupancy 18.8%) with LDS 67.6KB capping residency at 2 blocks/CU (2
// waves/SIMD). Each block now computes one 32-column w-half of out_n: stage1
// builds only that half of U (no duplicated MFMA), stage2 only those output
// columns (no duplicated MFMA); only the x load + bf16 convert duplicates
// (VALU had headroom). LDS halves to 33.8KB -> 4 blocks/CU (16 waves/CU),
// and acc1/acc2/bu halve so VGPRs fit the 128-reg/4-waves-per-SIMD budget.
// R5's ks=6,7 cross-barrier aw refill is replaced by next-k aw loads issued
// between stage1(k+1) and the barrier: the barrier's vmcnt(0) drain
// completes them for free, and aw stays dead across stage1 (register peak
// ~115-125 in both phases; R2/R3 lesson: never cap regs below liveness).
// Pair-swizzle puts (n,wh=0)/(n,wh=1) on the same XCD 8 raw-bids apart so
// the second read of x[n] is L2-hot (FETCH_SIZE stays flat).

typedef __attribute__((ext_vector_type(8))) short bf16x8;
typedef __attribute__((ext_vector_type(4))) float f32x4;

__device__ __forceinline__ short f2bf(float f) {
  union { float f; unsigned u; } c; c.f = f;
  unsigned r = c.u + 0x7FFFu + ((c.u >> 16) & 1u);   // RNE
  return (short)(r >> 16);
}

__device__ __forceinline__ unsigned pkbf(float a, float b) {
  float2 t; t.x = a; t.y = b;
  union { __hip_bfloat162 h; unsigned u; } c;
  c.h = __float22bfloat162_rn(t);   // v_cvt_pk_bf16_f32, RNE
  return c.u;
}

// ---------------- workspace layout (bytes) ----------------
// Wsw   : short[196608] @ 0        fragment-ordered W  (k,wv4,mt4,ks8,lane,e)
// Asw   : short[12288]  @ 393216   fragment-ordered A^T (k,ks,nt,lane,e)
// biasCM: float[16384]  @ 417792   column-major bias: biasCM[w*256 + d]
#define ASW_OFF  393216
#define BIAS_OFF 417792

__global__ __launch_bounds__(256) void prep_kernel(
    const float* __restrict__ W, const float* __restrict__ b,
    const float* __restrict__ A, short* __restrict__ Wsw,
    short* __restrict__ Asw, float* __restrict__ biasCM) {
  int t = blockIdx.x * 256 + threadIdx.x;
  if (t < 196608) {
    // Wsw flat = ((((k*4+wv)*4+mt)*8+ks)*64 + lane)*8 + e
    int e = t & 7, l = (t >> 3) & 63, ks = (t >> 9) & 7, mt = (t >> 12) & 3,
        wv = (t >> 14) & 3, k = t >> 16;
    int d = 64 * wv + 16 * mt + (l & 15);
    int c = 32 * ks + 8 * (l >> 4) + e;
    Wsw[t] = f2bf(W[(k * 256 + d) * 256 + c]);
  } else if (t < 196608 + 12288) {
    // Asw flat = (((k*2+ks)*4+nt)*64 + lane)*8 + e ; value = A[k][v][w]
    int t2 = t - 196608;
    int e = t2 & 7, l = (t2 >> 3) & 63, nt = (t2 >> 9) & 3, ks = (t2 >> 11) & 1,
        k = t2 >> 12;
    int w = nt * 16 + (l & 15);
    int v = ks * 32 + (l >> 4) * 8 + e;
    Asw[t2] = f2bf(A[(k * 64 + v) * 64 + w]);
  } else {
    // biasCM[w*256 + d] = sum_k (sum_v A[k][v][w]) * b[k][d]
    int t2 = t - 196608 - 12288;
    int w = t2 >> 8, d = t2 & 255;
    float s = 0.f;
    for (int k = 0; k < 3; ++k) {
      float cs = 0.f;
#pragma unroll
      for (int v = 0; v < 64; ++v) cs += A[(k * 64 + v) * 64 + w];
      s += cs * b[k * 256 + d];
    }
    biasCM[t2] = s;
  }
}

#define UT_STRIDE 264  // bf16 elems per Ut row (256 + 8 pad), 528B rows

// stage-1: compute the block's 32 w-columns of U_k for rows [64wv,64wv+64),
// write transposed into Utw (rows = local w 0..31)
__device__ __forceinline__ void stage1(
    const short* __restrict__ Asw, int k, const bf16x8 (&xf)[2][4],
    short* __restrict__ Utw, int wh, int wv, int lane, int li, int lq) {
  const short* AswK = Asw + k * 4096;
  f32x4 acc1[4][2];
#pragma unroll
  for (int mt = 0; mt < 4; ++mt)
#pragma unroll
    for (int nt = 0; nt < 2; ++nt)
      acc1[mt][nt] = (f32x4){0.f, 0.f, 0.f, 0.f};

#pragma unroll
  for (int ks = 0; ks < 2; ++ks) {
    bf16x8 bfr[2];
#pragma unroll
    for (int nt = 0; nt < 2; ++nt)
      bfr[nt] = *(const bf16x8*)(AswK + ((ks * 4 + 2 * wh + nt) * 64 + lane) * 8);
#pragma unroll
    for (int mt = 0; mt < 4; ++mt)
#pragma unroll
      for (int nt = 0; nt < 2; ++nt)
        acc1[mt][nt] = __builtin_amdgcn_mfma_f32_16x16x32_bf16(
            xf[ks][mt], bfr[nt], acc1[mt][nt], 0, 0, 0);
  }

#pragma unroll
  for (int mt = 0; mt < 4; ++mt)
#pragma unroll
    for (int nt = 0; nt < 2; ++nt) {
      int w = nt * 16 + li;                    // local w row 0..31
      int ct = 64 * wv + 16 * mt + 4 * lq;
      union { unsigned u[2]; unsigned long long ull; } p;
      p.u[0] = pkbf(acc1[mt][nt][0], acc1[mt][nt][1]);
      p.u[1] = pkbf(acc1[mt][nt][2], acc1[mt][nt][3]);
      *(unsigned long long*)(&Utw[w * UT_STRIDE + ct]) = p.ull;
    }
}

__global__ __launch_bounds__(256, 4) void gcn_main(
    const float* __restrict__ x, const short* __restrict__ Wsw,
    const short* __restrict__ Asw, const float* __restrict__ biasCM,
    float* __restrict__ out) {
  __shared__ short UtA[32 * UT_STRIDE];  // 16896 B each; 33792 total
  __shared__ short UtB[32 * UT_STRIDE];

  const int tid = threadIdx.x;
  const int wv = tid >> 6;        // wave 0..3, owns d-rows [64wv, 64wv+64)
  const int lane = tid & 63;
  const int li = lane & 15;
  const int lq = lane >> 4;

  // pair-swizzle: raw bids b and b+8 share n (same XCD via b%8), wh = 0/1
  const int b = blockIdx.x;
  const int n = ((b >> 4) << 3) | (b & 7);
  const int wh = (b >> 3) & 1;    // w-half: columns [32wh, 32wh+32)

  const float* xn = x + (size_t)n * 16384;
  float* outn = out + (size_t)n * 16384;

  // ---- acc2 init = bias (epilogue becomes a pure store); biasCM is L2-hot
  f32x4 acc2[4][2];
#pragma unroll
  for (int mt = 0; mt < 4; ++mt)
#pragma unroll
    for (int nt = 0; nt < 2; ++nt) {
      const float4 bb = *(const float4*)(biasCM + (32 * wh + nt * 16 + li) * 256 +
                                         64 * wv + 16 * mt + 4 * lq);
      acc2[mt][nt] = (f32x4){bb.x, bb.y, bb.z, bb.w};
    }

  // ---- stage-1 A-operand: wave's 64x64 block of Xn, registers, k-invariant
  bf16x8 xf[2][4];
#pragma unroll
  for (int ks = 0; ks < 2; ++ks)
#pragma unroll
    for (int mt = 0; mt < 4; ++mt) {
      const float4* p =
          (const float4*)(xn + (64 * wv + 16 * mt + li) * 64 + 32 * ks + 8 * lq);
      float4 f0 = p[0], f1 = p[1];
      union { bf16x8 v; unsigned u[4]; } t;
      t.u[0] = pkbf(f0.x, f0.y); t.u[1] = pkbf(f0.z, f0.w);
      t.u[2] = pkbf(f1.x, f1.y); t.u[3] = pkbf(f1.z, f1.w);
      xf[ks][mt] = t.v;
    }

  // ---- preamble: U_0 half -> UtA; aw(k=0, ks=0,1) loads drain at the barrier
  stage1(Asw, 0, xf, UtA, wh, wv, lane, li, lq);

  bf16x8 awA[4], awB[4];
  {
    const short* W0 = Wsw + (0 * 4 + wv) * 16384;
#pragma unroll
    for (int mt = 0; mt < 4; ++mt) {
      awA[mt] = *(const bf16x8*)(W0 + ((mt * 8 + 0) * 64 + lane) * 8);
      awB[mt] = *(const bf16x8*)(W0 + ((mt * 8 + 1) * 64 + lane) * 8);
    }
  }

  __syncthreads();  // UtA complete; aw(k=0) complete (vmcnt drain)

#pragma unroll
  for (int k = 0; k < 3; ++k) {
    const short* Utr = (k & 1) ? UtB : UtA;
    short* Utw = (k & 1) ? UtA : UtB;
    const short* WswK = Wsw + (k * 4 + wv) * 16384;

    // ---------- stage 2: acc2 += W_k[rows 64wv..] @ U_k-half (from Utr) ----
#pragma unroll
    for (int ks = 0; ks < 8; ++ks) {
      bf16x8 bu[2];
#pragma unroll
      for (int nt = 0; nt < 2; ++nt)
        bu[nt] = *(const bf16x8*)(&Utr[(nt * 16 + li) * UT_STRIDE + 32 * ks + 8 * lq]);

      bf16x8 aw0[4];
#pragma unroll
      for (int mt = 0; mt < 4; ++mt) aw0[mt] = (ks & 1) ? awB[mt] : awA[mt];

      // depth-2 rotate within the superstep; no cross-barrier refill (keeps
      // aw dead across stage1 -> VGPR peak fits the 4-waves/SIMD budget)
      if (ks < 6) {
#pragma unroll
        for (int mt = 0; mt < 4; ++mt) {
          bf16x8 nv = *(const bf16x8*)(WswK + ((mt * 8 + ks + 2) * 64 + lane) * 8);
          if (ks & 1) awB[mt] = nv; else awA[mt] = nv;
        }
      }

#pragma unroll
      for (int mt = 0; mt < 4; ++mt)
#pragma unroll
        for (int nt = 0; nt < 2; ++nt)
          acc2[mt][nt] = __builtin_amdgcn_mfma_f32_16x16x32_bf16(
              aw0[mt], bu[nt], acc2[mt][nt], 0, 0, 0);
    }

    // ---------- stage 1 of k+1 into the other buffer, then aw(k+1) loads;
    // the barrier's vmcnt(0) drain completes them before any wave proceeds
    if (k < 2) {
      stage1(Asw, k + 1, xf, Utw, wh, wv, lane, li, lq);
      const short* WN = Wsw + ((k + 1) * 4 + wv) * 16384;
#pragma unroll
      for (int mt = 0; mt < 4; ++mt) {
        awA[mt] = *(const bf16x8*)(WN + ((mt * 8 + 0) * 64 + lane) * 8);
        awB[mt] = *(const bf16x8*)(WN + ((mt * 8 + 1) * 64 + lane) * 8);
      }
      __syncthreads();  // Utw complete; also fences this superstep's Utr reads
    }
  }

  // ---------- epilogue: direct float4 stores from C-layout ----------
  // d = 64wv+16mt+4lq+r -> c = 8wv+2mt+(lq>>1), t = 4(lq&1)+r
  // w = 32wh + 16nt + li
#pragma unroll
  for (int mt = 0; mt < 4; ++mt)
#pragma unroll
    for (int nt = 0; nt < 2; ++nt) {
      float4 vv;
      vv.x = acc2[mt][nt][0];
      vv.y = acc2[mt][nt][1];
      vv.z = acc2[mt][nt][2];
      vv.w = acc2[mt][nt][3];
      *(float4*)(outn + (8 * wv + 2 * mt + (lq >> 1)) * 512 +
                 (32 * wh + nt * 16 + li) * 8 + 4 * (lq & 1)) = vv;
    }
}

extern "C" void kernel_launch(void* const* d_in, const int* in_sizes, int n_in,
                              void* d_out, int out_size, void* d_ws, size_t ws_size,
                              hipStream_t stream) {
  (void)in_sizes; (void)n_in; (void)out_size; (void)ws_size;
  const float* x = (const float*)d_in[0];
  const float* W = (const float*)d_in[1];
  const float* b = (const float*)d_in[2];
  const float* A = (const float*)d_in[3];
  float* out = (float*)d_out;

  short* Wsw = (short*)d_ws;
  short* Asw = (short*)((char*)d_ws + ASW_OFF);
  float* biasCM = (float*)((char*)d_ws + BIAS_OFF);

  // prep: 196608 (W) + 12288 (A) + 16384 (bias) = 225280 threads = 880 blocks
  prep_kernel<<<880, 256, 0, stream>>>(W, b, A, Wsw, Asw, biasCM);
  // 2048 blocks: (n, w-half) pairs, pair-swizzled onto the same XCD
  gcn_main<<<2048, 256, 0, stream>>>(x, Wsw, Asw, biasCM, out);
}

// Round 2
// 160.198 us; speedup vs baseline: 1.0901x; 1.0901x over previous
//
#include <hip/hip_runtime.h>
#include <hip/hip_bf16.h>

// Problem constants: N=1024, C=32, T=8, V=64, K=3, CT=256
// out[n][c][v][t] = sum_k sum_j W[k][c*8+t][j] * U_k[j][v] + bias2T[c*8+t][v]
// U_k[j][v] = sum_u x[n][j][u] * A[k][u][v]
//
// R7: R6's w-split x2 (good: MFMA cycles unchanged, LDS 33.8KB, occupancy
// 2x) but with the register cap REVERTED to __launch_bounds__(256,2).
// R6's (256,4) forced a 64-VGPR tier under ~125 liveness -> spill (+10MB
// WRITE_SIZE, dur 59->84us) — exactly the R2/R3 lesson. Occupancy comes
// from ACTUAL reg usage: allocator should land ~110-125 (R5 landed 116
// with MORE live state), giving 4 blocks/CU from LDS alone; worst case
// 3 blocks/CU at ~130 regs. Either way: no spill.
//
// Structure recap: each block computes one 32-column w-half of out_n.
// stage1 builds that half of U_k (no dup MFMA), stage2 those output
// columns (no dup MFMA); only x load + bf16 convert duplicates (VALU has
// headroom). Pair-swizzle puts (n,wh=0)/(n,wh=1) 8 raw-bids apart -> same
// XCD -> second x[n] read is L2-hot (R6 confirmed: FETCH +4MB only).
// aw(k+1) loads issue between stage1(k+1) and the barrier; the barrier's
// vmcnt(0) drain completes them for free.

typedef __attribute__((ext_vector_type(8))) short bf16x8;
typedef __attribute__((ext_vector_type(4))) float f32x4;

__device__ __forceinline__ short f2bf(float f) {
  union { float f; unsigned u; } c; c.f = f;
  unsigned r = c.u + 0x7FFFu + ((c.u >> 16) & 1u);   // RNE
  return (short)(r >> 16);
}

__device__ __forceinline__ unsigned pkbf(float a, float b) {
  float2 t; t.x = a; t.y = b;
  union { __hip_bfloat162 h; unsigned u; } c;
  c.h = __float22bfloat162_rn(t);   // v_cvt_pk_bf16_f32, RNE
  return c.u;
}

// ---------------- workspace layout (bytes) ----------------
// Wsw   : short[196608] @ 0        fragment-ordered W  (k,wv4,mt4,ks8,lane,e)
// Asw   : short[12288]  @ 393216   fragment-ordered A^T (k,ks,nt,lane,e)
// biasCM: float[16384]  @ 417792   column-major bias: biasCM[w*256 + d]
#define ASW_OFF  393216
#define BIAS_OFF 417792

__global__ __launch_bounds__(256) void prep_kernel(
    const float* __restrict__ W, const float* __restrict__ b,
    const float* __restrict__ A, short* __restrict__ Wsw,
    short* __restrict__ Asw, float* __restrict__ biasCM) {
  int t = blockIdx.x * 256 + threadIdx.x;
  if (t < 196608) {
    // Wsw flat = ((((k*4+wv)*4+mt)*8+ks)*64 + lane)*8 + e
    int e = t & 7, l = (t >> 3) & 63, ks = (t >> 9) & 7, mt = (t >> 12) & 3,
        wv = (t >> 14) & 3, k = t >> 16;
    int d = 64 * wv + 16 * mt + (l & 15);
    int c = 32 * ks + 8 * (l >> 4) + e;
    Wsw[t] = f2bf(W[(k * 256 + d) * 256 + c]);
  } else if (t < 196608 + 12288) {
    // Asw flat = (((k*2+ks)*4+nt)*64 + lane)*8 + e ; value = A[k][v][w]
    int t2 = t - 196608;
    int e = t2 & 7, l = (t2 >> 3) & 63, nt = (t2 >> 9) & 3, ks = (t2 >> 11) & 1,
        k = t2 >> 12;
    int w = nt * 16 + (l & 15);
    int v = ks * 32 + (l >> 4) * 8 + e;
    Asw[t2] = f2bf(A[(k * 64 + v) * 64 + w]);
  } else {
    // biasCM[w*256 + d] = sum_k (sum_v A[k][v][w]) * b[k][d]
    int t2 = t - 196608 - 12288;
    int w = t2 >> 8, d = t2 & 255;
    float s = 0.f;
    for (int k = 0; k < 3; ++k) {
      float cs = 0.f;
#pragma unroll
      for (int v = 0; v < 64; ++v) cs += A[(k * 64 + v) * 64 + w];
      s += cs * b[k * 256 + d];
    }
    biasCM[t2] = s;
  }
}

#define UT_STRIDE 264  // bf16 elems per Ut row (256 + 8 pad), 528B rows

// stage-1: compute the block's 32 w-columns of U_k for rows [64wv,64wv+64),
// write transposed into Utw (rows = local w 0..31)
__device__ __forceinline__ void stage1(
    const short* __restrict__ Asw, int k, const bf16x8 (&xf)[2][4],
    short* __restrict__ Utw, int wh, int wv, int lane, int li, int lq) {
  const short* AswK = Asw + k * 4096;
  f32x4 acc1[4][2];
#pragma unroll
  for (int mt = 0; mt < 4; ++mt)
#pragma unroll
    for (int nt = 0; nt < 2; ++nt)
      acc1[mt][nt] = (f32x4){0.f, 0.f, 0.f, 0.f};

#pragma unroll
  for (int ks = 0; ks < 2; ++ks) {
    bf16x8 bfr[2];
#pragma unroll
    for (int nt = 0; nt < 2; ++nt)
      bfr[nt] = *(const bf16x8*)(AswK + ((ks * 4 + 2 * wh + nt) * 64 + lane) * 8);
#pragma unroll
    for (int mt = 0; mt < 4; ++mt)
#pragma unroll
      for (int nt = 0; nt < 2; ++nt)
        acc1[mt][nt] = __builtin_amdgcn_mfma_f32_16x16x32_bf16(
            xf[ks][mt], bfr[nt], acc1[mt][nt], 0, 0, 0);
  }

#pragma unroll
  for (int mt = 0; mt < 4; ++mt)
#pragma unroll
    for (int nt = 0; nt < 2; ++nt) {
      int w = nt * 16 + li;                    // local w row 0..31
      int ct = 64 * wv + 16 * mt + 4 * lq;
      union { unsigned u[2]; unsigned long long ull; } p;
      p.u[0] = pkbf(acc1[mt][nt][0], acc1[mt][nt][1]);
      p.u[1] = pkbf(acc1[mt][nt][2], acc1[mt][nt][3]);
      *(unsigned long long*)(&Utw[w * UT_STRIDE + ct]) = p.ull;
    }
}

__global__ __launch_bounds__(256, 2) void gcn_main(
    const float* __restrict__ x, const short* __restrict__ Wsw,
    const short* __restrict__ Asw, const float* __restrict__ biasCM,
    float* __restrict__ out) {
  __shared__ short UtA[32 * UT_STRIDE];  // 16896 B each; 33792 total
  __shared__ short UtB[32 * UT_STRIDE];

  const int tid = threadIdx.x;
  const int wv = tid >> 6;        // wave 0..3, owns d-rows [64wv, 64wv+64)
  const int lane = tid & 63;
  const int li = lane & 15;
  const int lq = lane >> 4;

  // pair-swizzle: raw bids b and b+8 share n (same XCD via b%8), wh = 0/1
  const int b = blockIdx.x;
  const int n = ((b >> 4) << 3) | (b & 7);
  const int wh = (b >> 3) & 1;    // w-half: columns [32wh, 32wh+32)

  const float* xn = x + (size_t)n * 16384;
  float* outn = out + (size_t)n * 16384;

  // ---- acc2 init = bias (epilogue becomes a pure store); biasCM is L2-hot
  f32x4 acc2[4][2];
#pragma unroll
  for (int mt = 0; mt < 4; ++mt)
#pragma unroll
    for (int nt = 0; nt < 2; ++nt) {
      const float4 bb = *(const float4*)(biasCM + (32 * wh + nt * 16 + li) * 256 +
                                         64 * wv + 16 * mt + 4 * lq);
      acc2[mt][nt] = (f32x4){bb.x, bb.y, bb.z, bb.w};
    }

  // ---- stage-1 A-operand: wave's 64x64 block of Xn, registers, k-invariant
  bf16x8 xf[2][4];
#pragma unroll
  for (int ks = 0; ks < 2; ++ks)
#pragma unroll
    for (int mt = 0; mt < 4; ++mt) {
      const float4* p =
          (const float4*)(xn + (64 * wv + 16 * mt + li) * 64 + 32 * ks + 8 * lq);
      float4 f0 = p[0], f1 = p[1];
      union { bf16x8 v; unsigned u[4]; } t;
      t.u[0] = pkbf(f0.x, f0.y); t.u[1] = pkbf(f0.z, f0.w);
      t.u[2] = pkbf(f1.x, f1.y); t.u[3] = pkbf(f1.z, f1.w);
      xf[ks][mt] = t.v;
    }

  // ---- preamble: U_0 half -> UtA; aw(k=0, ks=0,1) loads drain at the barrier
  stage1(Asw, 0, xf, UtA, wh, wv, lane, li, lq);

  bf16x8 awA[4], awB[4];
  {
    const short* W0 = Wsw + (0 * 4 + wv) * 16384;
#pragma unroll
    for (int mt = 0; mt < 4; ++mt) {
      awA[mt] = *(const bf16x8*)(W0 + ((mt * 8 + 0) * 64 + lane) * 8);
      awB[mt] = *(const bf16x8*)(W0 + ((mt * 8 + 1) * 64 + lane) * 8);
    }
  }

  __syncthreads();  // UtA complete; aw(k=0) complete (vmcnt drain)

#pragma unroll
  for (int k = 0; k < 3; ++k) {
    const short* Utr = (k & 1) ? UtB : UtA;
    short* Utw = (k & 1) ? UtA : UtB;
    const short* WswK = Wsw + (k * 4 + wv) * 16384;

    // ---------- stage 2: acc2 += W_k[rows 64wv..] @ U_k-half (from Utr) ----
#pragma unroll
    for (int ks = 0; ks < 8; ++ks) {
      bf16x8 bu[2];
#pragma unroll
      for (int nt = 0; nt < 2; ++nt)
        bu[nt] = *(const bf16x8*)(&Utr[(nt * 16 + li) * UT_STRIDE + 32 * ks + 8 * lq]);

      bf16x8 aw0[4];
#pragma unroll
      for (int mt = 0; mt < 4; ++mt) aw0[mt] = (ks & 1) ? awB[mt] : awA[mt];

      // depth-2 rotate within the superstep; no cross-barrier refill (keeps
      // aw dead across stage1)
      if (ks < 6) {
#pragma unroll
        for (int mt = 0; mt < 4; ++mt) {
          bf16x8 nv = *(const bf16x8*)(WswK + ((mt * 8 + ks + 2) * 64 + lane) * 8);
          if (ks & 1) awB[mt] = nv; else awA[mt] = nv;
        }
      }

#pragma unroll
      for (int mt = 0; mt < 4; ++mt)
#pragma unroll
        for (int nt = 0; nt < 2; ++nt)
          acc2[mt][nt] = __builtin_amdgcn_mfma_f32_16x16x32_bf16(
              aw0[mt], bu[nt], acc2[mt][nt], 0, 0, 0);
    }

    // ---------- stage 1 of k+1 into the other buffer, then aw(k+1) loads;
    // the barrier's vmcnt(0) drain completes them before any wave proceeds
    if (k < 2) {
      stage1(Asw, k + 1, xf, Utw, wh, wv, lane, li, lq);
      const short* WN = Wsw + ((k + 1) * 4 + wv) * 16384;
#pragma unroll
      for (int mt = 0; mt < 4; ++mt) {
        awA[mt] = *(const bf16x8*)(WN + ((mt * 8 + 0) * 64 + lane) * 8);
        awB[mt] = *(const bf16x8*)(WN + ((mt * 8 + 1) * 64 + lane) * 8);
      }
      __syncthreads();  // Utw complete; also fences this superstep's Utr reads
    }
  }

  // ---------- epilogue: direct float4 stores from C-layout ----------
  // d = 64wv+16mt+4lq+r -> c = 8wv+2mt+(lq>>1), t = 4(lq&1)+r
  // w = 32wh + 16nt + li
#pragma unroll
  for (int mt = 0; mt < 4; ++mt)
#pragma unroll
    for (int nt = 0; nt < 2; ++nt) {
      float4 vv;
      vv.x = acc2[mt][nt][0];
      vv.y = acc2[mt][nt][1];
      vv.z = acc2[mt][nt][2];
      vv.w = acc2[mt][nt][3];
      *(float4*)(outn + (8 * wv + 2 * mt + (lq >> 1)) * 512 +
                 (32 * wh + nt * 16 + li) * 8 + 4 * (lq & 1)) = vv;
    }
}

extern "C" void kernel_launch(void* const* d_in, const int* in_sizes, int n_in,
                              void* d_out, int out_size, void* d_ws, size_t ws_size,
                              hipStream_t stream) {
  (void)in_sizes; (void)n_in; (void)out_size; (void)ws_size;
  const float* x = (const float*)d_in[0];
  const float* W = (const float*)d_in[1];
  const float* b = (const float*)d_in[2];
  const float* A = (const float*)d_in[3];
  float* out = (float*)d_out;

  short* Wsw = (short*)d_ws;
  short* Asw = (short*)((char*)d_ws + ASW_OFF);
  float* biasCM = (float*)((char*)d_ws + BIAS_OFF);

  // prep: 196608 (W) + 12288 (A) + 16384 (bias) = 225280 threads = 880 blocks
  prep_kernel<<<880, 256, 0, stream>>>(W, b, A, Wsw, Asw, biasCM);
  // 2048 blocks: (n, w-half) pairs, pair-swizzled onto the same XCD
  gcn_main<<<2048, 256, 0, stream>>>(x, Wsw, Asw, biasCM, out);
}

// Round 3
// 147.667 us; speedup vs baseline: 1.1826x; 1.0849x over previous
//
#include <hip/hip_runtime.h>
#include <hip/hip_bf16.h>

// Problem constants: N=1024, C=32, T=8, V=64, K=3, CT=256
// out[n][c][v][t] = sum_k sum_j W[k][c*8+t][j] * U_k[j][v] + bias2T[c*8+t][v]
// U_k[j][v] = sum_u x[n][j][u] * A[k][u][v]
//
// R8: R5's exact compute structure (full-n blocks, xf register-resident,
// nt=4-thick 16-MFMA runs per ks-step, depth-2 aw rotate with cross-k
// refill) + SINGLE Ut buffer (33.8KB -> 4 blocks/CU, 16 waves/CU) + raw
// lgkm-only barriers (s_waitcnt lgkmcnt(0); s_barrier) so aw prefetches
// stay in flight across barriers (no vmcnt(0) drain).
// R6 lesson: never cap regs below liveness (spill = +10MB WRITE_SIZE).
// R7 lesson: never thin the per-ks MFMA run (nt=2 halves latency cover);
// occupancy must come from LDS, not from splitting work.
// Raw-barrier safety: all cross-wave comm is via LDS; every wave drains
// lgkmcnt(0) before s_barrier, so its LDS reads/writes are complete before
// any wave passes. Global loads (aw/xf/bias) are wave-private -> vmcnt may
// legally stay outstanding across the barrier (compiler waits at use).

typedef __attribute__((ext_vector_type(8))) short bf16x8;
typedef __attribute__((ext_vector_type(4))) float f32x4;

#define RAWBAR() asm volatile("s_waitcnt lgkmcnt(0)\n\ts_barrier" ::: "memory")

__device__ __forceinline__ short f2bf(float f) {
  union { float f; unsigned u; } c; c.f = f;
  unsigned r = c.u + 0x7FFFu + ((c.u >> 16) & 1u);   // RNE
  return (short)(r >> 16);
}

__device__ __forceinline__ unsigned pkbf(float a, float b) {
  float2 t; t.x = a; t.y = b;
  union { __hip_bfloat162 h; unsigned u; } c;
  c.h = __float22bfloat162_rn(t);   // v_cvt_pk_bf16_f32, RNE
  return c.u;
}

// ---------------- workspace layout (bytes) ----------------
// Wsw   : short[196608] @ 0        fragment-ordered W  (k,wv4,mt4,ks8,lane,e)
// Asw   : short[12288]  @ 393216   fragment-ordered A^T (k,ks,nt,lane,e)
// biasCM: float[16384]  @ 417792   column-major bias: biasCM[w*256 + d]
#define ASW_OFF  393216
#define BIAS_OFF 417792

__global__ __launch_bounds__(256) void prep_kernel(
    const float* __restrict__ W, const float* __restrict__ b,
    const float* __restrict__ A, short* __restrict__ Wsw,
    short* __restrict__ Asw, float* __restrict__ biasCM) {
  int t = blockIdx.x * 256 + threadIdx.x;
  if (t < 196608) {
    // Wsw flat = ((((k*4+wv)*4+mt)*8+ks)*64 + lane)*8 + e
    int e = t & 7, l = (t >> 3) & 63, ks = (t >> 9) & 7, mt = (t >> 12) & 3,
        wv = (t >> 14) & 3, k = t >> 16;
    int d = 64 * wv + 16 * mt + (l & 15);
    int c = 32 * ks + 8 * (l >> 4) + e;
    Wsw[t] = f2bf(W[(k * 256 + d) * 256 + c]);
  } else if (t < 196608 + 12288) {
    // Asw flat = (((k*2+ks)*4+nt)*64 + lane)*8 + e ; value = A[k][v][w]
    int t2 = t - 196608;
    int e = t2 & 7, l = (t2 >> 3) & 63, nt = (t2 >> 9) & 3, ks = (t2 >> 11) & 1,
        k = t2 >> 12;
    int w = nt * 16 + (l & 15);
    int v = ks * 32 + (l >> 4) * 8 + e;
    Asw[t2] = f2bf(A[(k * 64 + v) * 64 + w]);
  } else {
    // biasCM[w*256 + d] = sum_k (sum_v A[k][v][w]) * b[k][d]
    int t2 = t - 196608 - 12288;
    int w = t2 >> 8, d = t2 & 255;
    float s = 0.f;
    for (int k = 0; k < 3; ++k) {
      float cs = 0.f;
#pragma unroll
      for (int v = 0; v < 64; ++v) cs += A[(k * 64 + v) * 64 + w];
      s += cs * b[k * 256 + d];
    }
    biasCM[t2] = s;
  }
}

#define UT_STRIDE 264  // bf16 elems per Ut row (256 + 8 pad), 528B rows

// stage-1: compute U_k rows [64wv, 64wv+64), write transposed into Ut
__device__ __forceinline__ void stage1(
    const short* __restrict__ Asw, int k, const bf16x8 (&xf)[2][4],
    short* __restrict__ Utw, int wv, int lane, int li, int lq) {
  const short* AswK = Asw + k * 4096;
  f32x4 acc1[4][4];
#pragma unroll
  for (int mt = 0; mt < 4; ++mt)
#pragma unroll
    for (int nt = 0; nt < 4; ++nt)
      acc1[mt][nt] = (f32x4){0.f, 0.f, 0.f, 0.f};

#pragma unroll
  for (int ks = 0; ks < 2; ++ks) {
    bf16x8 bfr[4];
#pragma unroll
    for (int nt = 0; nt < 4; ++nt)
      bfr[nt] = *(const bf16x8*)(AswK + ((ks * 4 + nt) * 64 + lane) * 8);
#pragma unroll
    for (int mt = 0; mt < 4; ++mt)
#pragma unroll
      for (int nt = 0; nt < 4; ++nt)
        acc1[mt][nt] = __builtin_amdgcn_mfma_f32_16x16x32_bf16(
            xf[ks][mt], bfr[nt], acc1[mt][nt], 0, 0, 0);
  }

#pragma unroll
  for (int mt = 0; mt < 4; ++mt)
#pragma unroll
    for (int nt = 0; nt < 4; ++nt) {
      int w = nt * 16 + li;
      int ct = 64 * wv + 16 * mt + 4 * lq;
      union { unsigned u[2]; unsigned long long ull; } p;
      p.u[0] = pkbf(acc1[mt][nt][0], acc1[mt][nt][1]);
      p.u[1] = pkbf(acc1[mt][nt][2], acc1[mt][nt][3]);
      *(unsigned long long*)(&Utw[w * UT_STRIDE + ct]) = p.ull;
    }
}

__global__ __launch_bounds__(256, 2) void gcn_main(
    const float* __restrict__ x, const short* __restrict__ Wsw,
    const short* __restrict__ Asw, const float* __restrict__ biasCM,
    float* __restrict__ out) {
  __shared__ short Ut[64 * UT_STRIDE];  // 33792 B -> 4 blocks/CU

  const int tid = threadIdx.x;
  const int wv = tid >> 6;        // wave 0..3, owns d-rows [64wv, 64wv+64)
  const int lane = tid & 63;
  const int li = lane & 15;
  const int lq = lane >> 4;
  const int n = blockIdx.x;

  const float* xn = x + (size_t)n * 16384;
  float* outn = out + (size_t)n * 16384;

  // ---- acc2 init = bias (epilogue becomes a pure store); biasCM is L2-hot
  f32x4 acc2[4][4];
#pragma unroll
  for (int mt = 0; mt < 4; ++mt)
#pragma unroll
    for (int nt = 0; nt < 4; ++nt) {
      const float4 bb = *(const float4*)(biasCM + (nt * 16 + li) * 256 +
                                         64 * wv + 16 * mt + 4 * lq);
      acc2[mt][nt] = (f32x4){bb.x, bb.y, bb.z, bb.w};
    }

  // ---- stage-1 A-operand: wave's 64x64 block of Xn, registers, k-invariant
  bf16x8 xf[2][4];
#pragma unroll
  for (int ks = 0; ks < 2; ++ks)
#pragma unroll
    for (int mt = 0; mt < 4; ++mt) {
      const float4* p =
          (const float4*)(xn + (64 * wv + 16 * mt + li) * 64 + 32 * ks + 8 * lq);
      float4 f0 = p[0], f1 = p[1];
      union { bf16x8 v; unsigned u[4]; } t;
      t.u[0] = pkbf(f0.x, f0.y); t.u[1] = pkbf(f0.z, f0.w);
      t.u[2] = pkbf(f1.x, f1.y); t.u[3] = pkbf(f1.z, f1.w);
      xf[ks][mt] = t.v;
    }

  // ---- preamble: U_0 -> Ut; aw(k=0, ks=0,1) prefetch stays in flight
  stage1(Asw, 0, xf, Ut, wv, lane, li, lq);

  bf16x8 awA[4], awB[4];
  {
    const short* W0 = Wsw + (0 * 4 + wv) * 16384;
#pragma unroll
    for (int mt = 0; mt < 4; ++mt) {
      awA[mt] = *(const bf16x8*)(W0 + ((mt * 8 + 0) * 64 + lane) * 8);
      awB[mt] = *(const bf16x8*)(W0 + ((mt * 8 + 1) * 64 + lane) * 8);
    }
  }

  RAWBAR();  // Ut(k=0) visible; aw loads remain outstanding (no vmcnt drain)

#pragma unroll
  for (int k = 0; k < 3; ++k) {
    const short* WswK = Wsw + (k * 4 + wv) * 16384;
    const short* WswN = Wsw + ((k + 1) * 4 + wv) * 16384;  // next k (k<2 only)

    // ---------- stage 2: acc2 += W_k[rows 64wv..] @ U_k (from Ut) ----------
#pragma unroll
    for (int ks = 0; ks < 8; ++ks) {
      bf16x8 bu[4];
#pragma unroll
      for (int nt = 0; nt < 4; ++nt)
        bu[nt] = *(const bf16x8*)(&Ut[(nt * 16 + li) * UT_STRIDE + 32 * ks + 8 * lq]);

      bf16x8 aw0[4];
#pragma unroll
      for (int mt = 0; mt < 4; ++mt) aw0[mt] = (ks & 1) ? awB[mt] : awA[mt];

      // depth-2 rotate; at ks=6,7 refill from NEXT k's slice. These loads
      // cross the raw barriers without being drained (waited at use).
      if (ks < 6) {
#pragma unroll
        for (int mt = 0; mt < 4; ++mt) {
          bf16x8 nv = *(const bf16x8*)(WswK + ((mt * 8 + ks + 2) * 64 + lane) * 8);
          if (ks & 1) awB[mt] = nv; else awA[mt] = nv;
        }
      } else if (k < 2) {
#pragma unroll
        for (int mt = 0; mt < 4; ++mt) {
          bf16x8 nv = *(const bf16x8*)(WswN + ((mt * 8 + (ks - 6)) * 64 + lane) * 8);
          if (ks & 1) awB[mt] = nv; else awA[mt] = nv;
        }
      }

#pragma unroll
      for (int mt = 0; mt < 4; ++mt)
#pragma unroll
        for (int nt = 0; nt < 4; ++nt)
          acc2[mt][nt] = __builtin_amdgcn_mfma_f32_16x16x32_bf16(
              aw0[mt], bu[nt], acc2[mt][nt], 0, 0, 0);
    }

    // ---------- single-buffer handoff: WAR barrier, write U_{k+1}, RAW
    // barrier. Both are lgkm-only: every wave's LDS ops complete before it
    // enters the barrier, so reads(k) finish before writes(k+1) start.
    if (k < 2) {
      RAWBAR();                              // stage2(k) reads done (WAR)
      stage1(Asw, k + 1, xf, Ut, wv, lane, li, lq);
      RAWBAR();                              // Ut(k+1) visible (RAW)
    }
  }

  // ---------- epilogue: direct float4 stores from C-layout ----------
  // d = 64wv+16mt+4lq+r -> c = 8wv+2mt+(lq>>1), t = 4(lq&1)+r, w = 16nt+li
#pragma unroll
  for (int mt = 0; mt < 4; ++mt)
#pragma unroll
    for (int nt = 0; nt < 4; ++nt) {
      float4 vv;
      vv.x = acc2[mt][nt][0];
      vv.y = acc2[mt][nt][1];
      vv.z = acc2[mt][nt][2];
      vv.w = acc2[mt][nt][3];
      *(float4*)(outn + (8 * wv + 2 * mt + (lq >> 1)) * 512 +
                 (nt * 16 + li) * 8 + 4 * (lq & 1)) = vv;
    }
}

extern "C" void kernel_launch(void* const* d_in, const int* in_sizes, int n_in,
                              void* d_out, int out_size, void* d_ws, size_t ws_size,
                              hipStream_t stream) {
  (void)in_sizes; (void)n_in; (void)out_size; (void)ws_size;
  const float* x = (const float*)d_in[0];
  const float* W = (const float*)d_in[1];
  const float* b = (const float*)d_in[2];
  const float* A = (const float*)d_in[3];
  float* out = (float*)d_out;

  short* Wsw = (short*)d_ws;
  short* Asw = (short*)((char*)d_ws + ASW_OFF);
  float* biasCM = (float*)((char*)d_ws + BIAS_OFF);

  // prep: 196608 (W) + 12288 (A) + 16384 (bias) = 225280 threads = 880 blocks
  prep_kernel<<<880, 256, 0, stream>>>(W, b, A, Wsw, Asw, biasCM);
  gcn_main<<<1024, 256, 0, stream>>>(x, Wsw, Asw, biasCM, out);
}